// Round 13
// baseline (207.107 us; speedup 1.0000x reference)
//
#include <hip/hip_runtime.h>
#include <hip/hip_bf16.h>
#include <math.h>

// Problem constants
#define BN   4
#define CIN  128
#define COUT 256
#define HWP  4096      // 64*64

typedef __hip_bfloat16 bf16;
typedef __attribute__((ext_vector_type(8))) short sh8;    // 8 bf16 = 4 VGPR
typedef __attribute__((ext_vector_type(4))) float f32x4;  // MFMA accumulator

__device__ __forceinline__ float b2f(bf16 v) { return __bfloat162float(v); }
__device__ __forceinline__ float bflo(unsigned u) { return __uint_as_float(u << 16); }
__device__ __forceinline__ float bfhi(unsigned u) { return __uint_as_float(u & 0xffff0000u); }
__device__ __forceinline__ unsigned short f2bfbits(float f) {
    union { bf16 h; unsigned short u; } cv; cv.h = __float2bfloat16(f); return cv.u;
}
__device__ __forceinline__ float bfj(const uint4& c, int j) {
    unsigned u = (&c.x)[j >> 1];
    return (j & 1) ? bfhi(u) : bflo(u);
}

// ---------------------------------------------------------------- prep_all (+x transpose in blocks [0,256))
__global__ __launch_bounds__(256) void prep_all_kernel(
    const float* __restrict__ x, bf16* __restrict__ xt,
    const float* __restrict__ dc_w,
    const float* __restrict__ oc1_w, const float* __restrict__ oc1_b,
    const float* __restrict__ obn_g, const float* __restrict__ obn_b,
    const float* __restrict__ obn_m, const float* __restrict__ obn_v,
    const float* __restrict__ mc1_w, const float* __restrict__ mc1_b,
    const float* __restrict__ mbn_g, const float* __restrict__ mbn_b,
    const float* __restrict__ mbn_m, const float* __restrict__ mbn_v,
    const float* __restrict__ fu_w, const float* __restrict__ fu_b,
    const float* __restrict__ fbn_g, const float* __restrict__ fbn_b,
    const float* __restrict__ fbn_m, const float* __restrict__ fbn_v,
    const float* __restrict__ sa_w,
    const float* __restrict__ oc2_w, const float* __restrict__ mc2_w,
    const float* __restrict__ cb_pw_w,
    const float* __restrict__ cb_dw_b, const float* __restrict__ cbn_g,
    const float* __restrict__ cbn_b, const float* __restrict__ cbn_m,
    const float* __restrict__ cbn_v,
    bf16* __restrict__ wBf2, bf16* __restrict__ wCf2, float* __restrict__ ab,
    bf16* __restrict__ wFf, bf16* __restrict__ wSAf, float* __restrict__ fab,
    bf16* __restrict__ wDf, bf16* __restrict__ wPf, float* __restrict__ dwab)
{
    __shared__ bf16 t[64][136];
    if (blockIdx.x < 256) {
        const int b = blockIdx.x >> 6, chunk = blockIdx.x & 63;
        const int pos0 = chunk * 64;
        const int tid = threadIdx.x;
        const int lane = tid & 63, wv = tid >> 6;
        const float* xb = x + (size_t)b * CIN * HWP + pos0 + lane;
        #pragma unroll 4
        for (int j = 0; j < 32; j++) {
            int ci = wv * 32 + j;
            t[lane][ci] = __float2bfloat16(xb[(size_t)ci * HWP]);
        }
        __syncthreads();
        const int p = tid >> 2, cig = tid & 3;
        uint4* dst = (uint4*)(xt + ((size_t)b * HWP + pos0 + p) * 128 + cig * 32);
        const uint4* src = (const uint4*)&t[p][cig * 32];
        #pragma unroll
        for (int q = 0; q < 4; q++) dst[q] = src[q];
        return;
    }

    int o = (blockIdx.x - 256) * 256 + threadIdx.x;
    if (o < 294912) {
        int j = o & 7, o2 = o >> 3;
        int lane = o2 & 63, t_ = o2 >> 6;
        int l16 = lane & 15, quad = lane >> 4;
        int mt = t_ & 3, t2 = t_ >> 2;
        int kt = t2 % 18, t3 = t2 / 18;
        int h = t3 & 1, wv = t3 >> 1;
        int co = wv * 64 + mt * 16 + l16;
        int kkh = kt * 32 + quad * 8 + j;
        int k = kkh >> 6, ci = h * 64 + (kkh & 63);
        wBf2[o] = __float2bfloat16(dc_w[co * 1152 + ci * 9 + k]);
    } else if (o < 368640) {
        int idx = o - 294912;
        int j = idx & 7, o2 = idx >> 3;
        int lane = o2 & 63, t_ = o2 >> 6;
        int l16 = lane & 15, quad = lane >> 4;
        int kt = t_ % 18, t2 = t_ / 18;
        int h = t2 & 1, wv = t2 >> 1;
        int co = wv * 16 + l16;
        int kkh = kt * 32 + quad * 8 + j;
        int k = kkh >> 6, ci = h * 64 + (kkh & 63);
        float v = (co < 32) ? oc1_w[co * 1152 + ci * 9 + k]
                            : mc1_w[(co - 32) * 1152 + ci * 9 + k];
        wCf2[idx] = __float2bfloat16(v);
    } else if (o < 368704) {
        int c = o - 368640;
        float g, bb, m, vv, bias;
        if (c < 32) { g = obn_g[c]; bb = obn_b[c]; m = obn_m[c]; vv = obn_v[c]; bias = oc1_b[c]; }
        else { int c2 = c - 32; g = mbn_g[c2]; bb = mbn_b[c2]; m = mbn_m[c2]; vv = mbn_v[c2]; bias = mc1_b[c2]; }
        float alpha = g / sqrtf(vv + 1e-5f);
        ab[c] = alpha;
        ab[64 + c] = (bias - m) * alpha + bb;
    } else if (o < 467008) {
        int idx = o - 368704;
        int j = idx & 7, o2 = idx >> 3;
        int lane = o2 & 63, t_ = o2 >> 6;
        int l16 = lane & 15, quad = lane >> 4;
        int mt = t_ & 3, t2 = t_ >> 2;
        int kt = t2 % 12, wv = t2 / 12;
        int co = wv * 64 + mt * 16 + l16;
        int kk = kt * 32 + quad * 8 + j;
        wFf[idx] = __float2bfloat16(fu_w[co * 384 + kk]);
    } else if (o < 491584) {
        int idx = o - 467008;
        int j = idx & 7, o2 = idx >> 3;
        int lane = o2 & 63, t_ = o2 >> 6;
        int l16 = lane & 15, quad = lane >> 4;
        int kt = t_ % 12, wv = t_ / 12;
        int jr = wv * 16 + l16;
        int kk = kt * 32 + quad * 8 + j;
        wSAf[idx] = (jr < 49) ? __float2bfloat16(sa_w[kk * 49 + jr]) : __float2bfloat16(0.f);
    } else if (o < 491840) {
        int co = o - 491584;
        float alpha = fbn_g[co] / sqrtf(fbn_v[co] + 1e-5f);
        fab[co] = alpha;
        fab[256 + co] = (fu_b[co] - fbn_m[co]) * alpha + fbn_b[co];
    } else if (o < 510272) {
        int idx = o - 491840;
        int j = idx & 7, o2 = idx >> 3;
        int lane = o2 & 63, t_ = o2 >> 6;
        int l16 = lane & 15, quad = lane >> 4;
        int mt = t_ & 1, kt = t_ >> 1;
        int co = mt * 16 + l16;
        int kk = kt * 32 + quad * 8 + j;
        int k = kk >> 6, c = kk & 63;
        float v = 0.f;
        if (co < 18 && c < 32) v = oc2_w[co * 288 + c * 9 + k];
        else if (co >= 18 && co < 27 && c >= 32) v = mc2_w[(co - 18) * 288 + (c - 32) * 9 + k];
        wDf[idx] = __float2bfloat16(v);
    } else if (o < 526656) {
        int idx = o - 510272;
        int j = idx & 7, o2 = idx >> 3;
        int lane = o2 & 63, t_ = o2 >> 6;
        int l16 = lane & 15, quad = lane >> 4;
        int wv = t_ >> 3, kt = (t_ >> 1) & 3, mt = t_ & 1;
        int co = wv * 32 + mt * 16 + l16;
        int kk = kt * 32 + quad * 8 + j;
        wPf[idx] = __float2bfloat16(cb_pw_w[co * 128 + kk]);
    } else if (o < 526784) {
        int c = o - 526656;
        float alpha = cbn_g[c] / sqrtf(cbn_v[c] + 1e-5f);
        dwab[c] = alpha;
        dwab[128 + c] = (cb_dw_b[c] - cbn_m[c]) * alpha + cbn_b[c];
    }
}

// ---------------------------------------------------------------- conv1 (oc1+mc1) MFMA, 32px K-split -> ht
__global__ __launch_bounds__(256) void conv1_mfma_kernel(
    const bf16* __restrict__ xt, const bf16* __restrict__ wCf2, const float* __restrict__ ab,
    bf16* __restrict__ ht)
{
    __shared__ __align__(16) bf16 val[32][584];

    const int bid = blockIdx.x;
    const int b = (bid & 7) >> 1;
    const int tile = ((bid >> 3) << 1) | (bid & 1);
    const int pos0 = tile * 32;
    const int y = tile >> 1, x0 = (tile & 1) * 32;
    const int tid = threadIdx.x;
    const int lane = tid & 63, wv = tid >> 6;
    const int quad = lane >> 4, l16 = lane & 15;

    f32x4 acc[2] = {f32x4{0,0,0,0}, f32x4{0,0,0,0}};
    const bf16* xtb = xt + (size_t)b * HWP * 128;

    #pragma unroll
    for (int h = 0; h < 2; h++) {
        if (h) __syncthreads();
        {
            const int cig = tid & 7, pix = tid >> 3;
            const int ci0 = h * 64 + cig * 8;
            const int xxp = x0 + pix;
            #pragma unroll
            for (int k = 0; k < 9; k++) {
                int yy = y + k / 3 - 1, xx = xxp + k % 3 - 1;
                bool valid = (yy >= 0 && yy <= 63 && xx >= 0 && xx <= 63);
                uint4 c = {0, 0, 0, 0};
                if (valid) c = *(const uint4*)(xtb + (size_t)(yy * 64 + xx) * 128 + ci0);
                *(uint4*)&val[pix][k * 64 + cig * 8] = c;
            }
        }
        __syncthreads();

        const bf16* wl0 = wCf2 + ((size_t)(wv * 2 + h) * 18) * 512 + lane * 8;
        const bf16* vb0 = &val[l16][quad * 8];
        const bf16* vb1 = &val[16 + l16][quad * 8];
        for (int kt = 0; kt < 18; kt++) {
            sh8 af = *(const sh8*)(wl0 + kt * 512);
            sh8 b0 = *(const sh8*)(vb0 + kt * 32);
            sh8 b1 = *(const sh8*)(vb1 + kt * 32);
            acc[0] = __builtin_amdgcn_mfma_f32_16x16x32_bf16(af, b0, acc[0], 0, 0, 0);
            acc[1] = __builtin_amdgcn_mfma_f32_16x16x32_bf16(af, b1, acc[1], 0, 0, 0);
        }
    }

    const int co0 = wv * 16 + quad * 4;
    #pragma unroll
    for (int ph = 0; ph < 2; ph++) {
        float o0 = fmaxf(acc[ph][0] * ab[co0 + 0] + ab[64 + co0 + 0], 0.f);
        float o1 = fmaxf(acc[ph][1] * ab[co0 + 1] + ab[64 + co0 + 1], 0.f);
        float o2 = fmaxf(acc[ph][2] * ab[co0 + 2] + ab[64 + co0 + 2], 0.f);
        float o3 = fmaxf(acc[ph][3] * ab[co0 + 3] + ab[64 + co0 + 3], 0.f);
        uint2 pk;
        pk.x = (unsigned)f2bfbits(o0) | ((unsigned)f2bfbits(o1) << 16);
        pk.y = (unsigned)f2bfbits(o2) | ((unsigned)f2bfbits(o3) << 16);
        *(uint2*)(ht + ((size_t)b * HWP + pos0 + ph * 16 + l16) * 64 + co0) = pk;
    }
}

// ---------------------------------------------------------------- fused depthwise + pointwise + SA(contour)
__global__ __launch_bounds__(256) void dwpw_kernel(
    const bf16* __restrict__ xt, const float* __restrict__ dw_w, const float* __restrict__ dwab,
    const bf16* __restrict__ wPf, const float* __restrict__ pw_b,
    const bf16* __restrict__ wSAf, bf16* __restrict__ combined, float* __restrict__ part_b)
{
    __shared__ float wl[1152];
    __shared__ float abl[256];
    __shared__ __align__(16) bf16 vdw[16][136];
    const int bid = blockIdx.x;
    const int b = bid >> 8, tile = bid & 255;
    const int pos0 = tile * 16;
    const int y = tile >> 2, x0 = (tile & 3) * 16;
    const int tid = threadIdx.x;
    for (int i = tid; i < 1152; i += 256) wl[i] = dw_w[i];
    abl[tid] = dwab[tid];
    __syncthreads();

    {
        const int cig = tid & 15, pix = tid >> 4;
        const int ci0 = cig * 8;
        const int xxp = x0 + pix;
        const bf16* xtb = xt + (size_t)b * HWP * 128;
        float g[8] = {0, 0, 0, 0, 0, 0, 0, 0};
        #pragma unroll
        for (int k = 0; k < 9; k++) {
            int yy = y + k / 3 - 1, xx = xxp + k % 3 - 1;
            if (yy < 0 || yy > 63 || xx < 0 || xx > 63) continue;
            uint4 c = *(const uint4*)(xtb + (size_t)(yy * 64 + xx) * 128 + ci0);
            #pragma unroll
            for (int j = 0; j < 8; j++)
                g[j] += wl[(ci0 + j) * 9 + k] * bfj(c, j);
        }
        uint4 pk;
        float o[8];
        #pragma unroll
        for (int j = 0; j < 8; j++)
            o[j] = fmaxf(g[j] * abl[ci0 + j] + abl[128 + ci0 + j], 0.f);
        pk.x = (unsigned)f2bfbits(o[0]) | ((unsigned)f2bfbits(o[1]) << 16);
        pk.y = (unsigned)f2bfbits(o[2]) | ((unsigned)f2bfbits(o[3]) << 16);
        pk.z = (unsigned)f2bfbits(o[4]) | ((unsigned)f2bfbits(o[5]) << 16);
        pk.w = (unsigned)f2bfbits(o[6]) | ((unsigned)f2bfbits(o[7]) << 16);
        *(uint4*)&vdw[pix][ci0] = pk;
    }
    __syncthreads();

    const int lane = tid & 63, wv = tid >> 6;
    const int quad = lane >> 4, l16 = lane & 15;
    f32x4 acc[2] = {f32x4{0,0,0,0}, f32x4{0,0,0,0}};
    const bf16* fb = &vdw[l16][quad * 8];
    const bf16* wl0 = wPf + (size_t)wv * 4096 + lane * 8;
    #pragma unroll
    for (int kt = 0; kt < 4; kt++) {
        sh8 bf = *(const sh8*)(fb + kt * 32);
        #pragma unroll
        for (int mt = 0; mt < 2; mt++) {
            sh8 af = *(const sh8*)(wl0 + (kt * 2 + mt) * 512);
            acc[mt] = __builtin_amdgcn_mfma_f32_16x16x32_bf16(af, bf, acc[mt], 0, 0, 0);
        }
    }

    bf16* ct = combined + ((size_t)b * HWP + pos0 + l16) * 384 + 256;
    uint2 pko[2];
    #pragma unroll
    for (int mt = 0; mt < 2; mt++) {
        int co_b = wv * 32 + mt * 16 + quad * 4;
        uint2 pk;
        pk.x = (unsigned)f2bfbits(acc[mt][0] + pw_b[co_b])     | ((unsigned)f2bfbits(acc[mt][1] + pw_b[co_b + 1]) << 16);
        pk.y = (unsigned)f2bfbits(acc[mt][2] + pw_b[co_b + 2]) | ((unsigned)f2bfbits(acc[mt][3] + pw_b[co_b + 3]) << 16);
        *(uint2*)(ct + co_b) = pk;
        pko[mt] = pk;
    }

    // ---- Phase3: SA contribution for contour channels (global kt 8..11)
    __syncthreads();
    bf16* ct2 = &vdw[0][0];
    #pragma unroll
    for (int mt = 0; mt < 2; mt++) {
        int co_b = wv * 32 + mt * 16 + quad * 4;
        *(uint2*)(ct2 + l16 * 136 + co_b) = pko[mt];
    }
    __syncthreads();

    f32x4 sacc = {0, 0, 0, 0};
    const bf16* awl = wSAf + (size_t)wv * 6144 + lane * 8;
    #pragma unroll
    for (int kt2 = 0; kt2 < 4; kt2++) {
        sh8 af = *(const sh8*)(awl + (8 + kt2) * 512);
        sh8 bf2 = *(const sh8*)(ct2 + l16 * 136 + kt2 * 32 + quad * 8);
        sacc = __builtin_amdgcn_mfma_f32_16x16x32_bf16(af, bf2, sacc, 0, 0, 0);
    }
    #pragma unroll
    for (int r = 0; r < 4; r++) {
        int j = wv * 16 + quad * 4 + r;
        if (j < 49) part_b[(size_t)(j * BN + b) * HWP + pos0 + l16] = sacc[r];
    }
}

// ---------------------------------------------------------------- fused conv2 + deform + SA(main), co-split
// grid 1024 (b x 128 tiles x 2 co-halves), block 256 = 4 waves. LDS ~49 KB -> 3 blocks/CU.
__global__ __launch_bounds__(256) void deform_kernel(
    const bf16* __restrict__ xt, const bf16* __restrict__ ht, const bf16* __restrict__ wDf,
    const float* __restrict__ oc2_b, const float* __restrict__ mc2_b,
    const bf16* __restrict__ wBf2, const float* __restrict__ bias,
    const bf16* __restrict__ wSAf, bf16* __restrict__ combined, float* __restrict__ part_a)
{
    __shared__ __align__(16) bf16 val[32][584];
    __shared__ int   ti[288][4];
    __shared__ float tw[288][4];
    __shared__ float loff[18][32];
    __shared__ float lmsk[9][32];

    const int bid = blockIdx.x;
    const int b = (bid & 7) >> 1;                    // XCD-affinity
    const int rest = bid >> 3;                       // [0,128)
    const int ch = rest & 1;                         // co-half
    const int tile = (((rest >> 1) << 1) | (bid & 1));  // [0,128)
    const int pos0 = tile * 32;
    const int y = tile >> 1, x0 = (tile & 1) * 32;
    const int tid = threadIdx.x;
    const int lane = tid & 63, wv = tid >> 6;
    const int quad = lane >> 4, l16 = lane & 15;

    // ---- Phase A: conv2 (oc2+mc2) for this tile's 32 pixels (duplicated across co-halves)
    {
        const int cig = tid & 7, pix = tid >> 3;
        const int xxp = x0 + pix;
        const bf16* hb = ht + (size_t)b * HWP * 64;
        #pragma unroll
        for (int k = 0; k < 9; k++) {
            int yy = y + k / 3 - 1, xx = xxp + k % 3 - 1;
            bool valid = (yy >= 0 && yy <= 63 && xx >= 0 && xx <= 63);
            uint4 c = {0, 0, 0, 0};
            if (valid) c = *(const uint4*)(hb + (size_t)(yy * 64 + xx) * 64 + cig * 8);
            *(uint4*)&val[pix][k * 64 + cig * 8] = c;
        }
    }
    __syncthreads();
    {
        const int ph = wv >> 1, mt = wv & 1;
        f32x4 acc2 = {0, 0, 0, 0};
        const bf16* wl0 = wDf + ((size_t)mt * 64 + lane) * 8;
        const bf16* vbase = &val[ph * 16 + l16][quad * 8];
        for (int kt = 0; kt < 18; kt++) {
            sh8 af = *(const sh8*)(wl0 + kt * 1024);
            sh8 bf = *(const sh8*)(vbase + kt * 32);
            acc2 = __builtin_amdgcn_mfma_f32_16x16x32_bf16(af, bf, acc2, 0, 0, 0);
        }
        const int pix2 = ph * 16 + l16;
        #pragma unroll
        for (int r = 0; r < 4; r++) {
            int co = mt * 16 + quad * 4 + r;
            if (co < 18) {
                loff[co][pix2] = acc2[r] + oc2_b[co];
            } else if (co < 27) {
                float s = acc2[r] + mc2_b[co - 18];
                lmsk[co - 18][pix2] = 1.f / (1.f + expf(-s));
            }
        }
    }
    __syncthreads();

    // ---- Phase B: bilinear corner tables
    for (int e = tid; e < 288; e += 256) {
        int k = e >> 5, pix = e & 31;
        int pos = pos0 + pix;
        int yp = pos >> 6, xc = pos & 63;
        float offy = loff[2 * k][pix];
        float offx = loff[2 * k + 1][pix];
        float m = lmsk[k][pix];
        float py = (float)(yp - 1 + k / 3) + offy;
        float px = (float)(xc - 1 + k % 3) + offx;
        float fy = floorf(py), fx = floorf(px);
        float wy1 = py - fy, wx1 = px - fx;
        int y0 = (int)fy, x0c = (int)fx;
        int y1 = y0 + 1, x1 = x0c + 1;
        bool vy0 = (y0 >= 0 && y0 <= 63), vy1 = (y1 >= 0 && y1 <= 63);
        bool vx0 = (x0c >= 0 && x0c <= 63), vx1 = (x1 >= 0 && x1 <= 63);
        int cy0 = min(max(y0, 0), 63), cy1 = min(max(y1, 0), 63);
        int cx0 = min(max(x0c, 0), 63), cx1 = min(max(x1, 0), 63);
        ti[e][0] = cy0 * 64 + cx0;  tw[e][0] = (vy0 && vx0) ? (1.f - wy1) * (1.f - wx1) * m : 0.f;
        ti[e][1] = cy0 * 64 + cx1;  tw[e][1] = (vy0 && vx1) ? (1.f - wy1) * wx1 * m : 0.f;
        ti[e][2] = cy1 * 64 + cx0;  tw[e][2] = (vy1 && vx0) ? wy1 * (1.f - wx1) * m : 0.f;
        ti[e][3] = cy1 * 64 + cx1;  tw[e][3] = (vy1 && vx1) ? wy1 * wx1 * m : 0.f;
    }
    __syncthreads();

    // ---- Phase C/D: K-split gather + MFMA (this block: co [ch*128, ch*128+128))
    f32x4 acc[2][2] = {{f32x4{0,0,0,0}, f32x4{0,0,0,0}}, {f32x4{0,0,0,0}, f32x4{0,0,0,0}}};
    const bf16* xtb = xt + (size_t)b * HWP * 128;
    const int wv_o = ch * 2 + (wv >> 1);             // original weight wave index
    const int mtb = (wv & 1) * 2;                    // original mt base

    #pragma unroll
    for (int h = 0; h < 2; h++) {
        if (h) __syncthreads();
        {
            const int cig = tid & 7, pix = tid >> 3;
            const int ci0 = h * 64 + cig * 8;
            for (int k = 0; k < 9; k++) {
                const int e = k * 32 + pix;
                const int i0 = ti[e][0], i1 = ti[e][1], i2 = ti[e][2], i3 = ti[e][3];
                const float w0 = tw[e][0], w1 = tw[e][1], w2 = tw[e][2], w3 = tw[e][3];
                uint4 c0 = *(const uint4*)(xtb + (size_t)i0 * 128 + ci0);
                uint4 c1 = *(const uint4*)(xtb + (size_t)i1 * 128 + ci0);
                uint4 c2 = *(const uint4*)(xtb + (size_t)i2 * 128 + ci0);
                uint4 c3 = *(const uint4*)(xtb + (size_t)i3 * 128 + ci0);
                float g[8];
                #pragma unroll
                for (int j = 0; j < 8; j++)
                    g[j] = w0 * bfj(c0, j) + w1 * bfj(c1, j) + w2 * bfj(c2, j) + w3 * bfj(c3, j);
                uint4 pk;
                pk.x = (unsigned)f2bfbits(g[0]) | ((unsigned)f2bfbits(g[1]) << 16);
                pk.y = (unsigned)f2bfbits(g[2]) | ((unsigned)f2bfbits(g[3]) << 16);
                pk.z = (unsigned)f2bfbits(g[4]) | ((unsigned)f2bfbits(g[5]) << 16);
                pk.w = (unsigned)f2bfbits(g[6]) | ((unsigned)f2bfbits(g[7]) << 16);
                *(uint4*)&val[pix][k * 64 + cig * 8] = pk;
            }
        }
        __syncthreads();

        const bf16* wl0 = wBf2 + ((size_t)(wv_o * 2 + h) * 72) * 512 + lane * 8;
        const bf16* vb0 = &val[l16][quad * 8];
        const bf16* vb1 = &val[16 + l16][quad * 8];
        sh8 af[2], afn[2];
        #pragma unroll
        for (int m2 = 0; m2 < 2; m2++) af[m2] = *(const sh8*)(wl0 + (mtb + m2) * 512);
        for (int kt = 0; kt < 18; kt++) {
            sh8 b0 = *(const sh8*)(vb0 + kt * 32);
            sh8 b1 = *(const sh8*)(vb1 + kt * 32);
            if (kt < 17) {
                #pragma unroll
                for (int m2 = 0; m2 < 2; m2++)
                    afn[m2] = *(const sh8*)(wl0 + ((kt + 1) * 4 + mtb + m2) * 512);
            }
            #pragma unroll
            for (int m2 = 0; m2 < 2; m2++) {
                acc[m2][0] = __builtin_amdgcn_mfma_f32_16x16x32_bf16(af[m2], b0, acc[m2][0], 0, 0, 0);
                acc[m2][1] = __builtin_amdgcn_mfma_f32_16x16x32_bf16(af[m2], b1, acc[m2][1], 0, 0, 0);
            }
            #pragma unroll
            for (int m2 = 0; m2 < 2; m2++) af[m2] = afn[m2];
        }
    }

    // ---- epilogue: global comb write (co-local) + LDS transpose for SA
    uint2 pko[2][2];
    #pragma unroll
    for (int ph = 0; ph < 2; ph++) {
        bf16* ct = combined + ((size_t)b * HWP + pos0 + ph * 16 + l16) * 384;
        #pragma unroll
        for (int m2 = 0; m2 < 2; m2++) {
            int co = ch * 128 + wv * 32 + m2 * 16 + quad * 4;
            uint2 pk;
            pk.x = (unsigned)f2bfbits(acc[m2][ph][0] + bias[co])     | ((unsigned)f2bfbits(acc[m2][ph][1] + bias[co + 1]) << 16);
            pk.y = (unsigned)f2bfbits(acc[m2][ph][2] + bias[co + 2]) | ((unsigned)f2bfbits(acc[m2][ph][3] + bias[co + 3]) << 16);
            *(uint2*)(ct + co) = pk;
            pko[m2][ph] = pk;
        }
    }

    // ---- Phase E: partial SA for this co-half (global kt ch*4 .. ch*4+3)
    __syncthreads();
    bf16* ctile = &val[0][0];                        // [pix][co_local], stride 136
    #pragma unroll
    for (int ph = 0; ph < 2; ph++) {
        int pix = ph * 16 + l16;
        #pragma unroll
        for (int m2 = 0; m2 < 2; m2++) {
            int col = wv * 32 + m2 * 16 + quad * 4;
            *(uint2*)(ctile + pix * 136 + col) = pko[m2][ph];
        }
    }
    __syncthreads();

    f32x4 sacc[2] = {f32x4{0,0,0,0}, f32x4{0,0,0,0}};
    const bf16* awl = wSAf + (size_t)wv * 6144 + lane * 8;
    #pragma unroll
    for (int kt2 = 0; kt2 < 4; kt2++) {
        sh8 af = *(const sh8*)(awl + (ch * 4 + kt2) * 512);
        sh8 b0 = *(const sh8*)(ctile + l16 * 136 + kt2 * 32 + quad * 8);
        sh8 b1 = *(const sh8*)(ctile + (16 + l16) * 136 + kt2 * 32 + quad * 8);
        sacc[0] = __builtin_amdgcn_mfma_f32_16x16x32_bf16(af, b0, sacc[0], 0, 0, 0);
        sacc[1] = __builtin_amdgcn_mfma_f32_16x16x32_bf16(af, b1, sacc[1], 0, 0, 0);
    }
    float* pa = part_a + (size_t)ch * 802816;
    #pragma unroll
    for (int ph = 0; ph < 2; ph++) {
        #pragma unroll
        for (int r = 0; r < 4; r++) {
            int j = wv * 16 + quad * 4 + r;
            if (j < 49) pa[(size_t)(j * BN + b) * HWP + pos0 + ph * 16 + l16] = sacc[ph][r];
        }
    }
}

// ---------------------------------------------------------------- fusion 1x1 MFMA + in-block attn finalize
__global__ __launch_bounds__(256) void fuse_kernel(
    const bf16* __restrict__ combined, const float* __restrict__ part_a, const float* __restrict__ part_b,
    const float* __restrict__ sa_b,
    const bf16* __restrict__ wFf, const float* __restrict__ fab, float* __restrict__ out)
{
    __shared__ float sattn[16][17];
    __shared__ float lattn[16];

    const int bid = blockIdx.x;
    const int b = bid >> 8, tile = bid & 255;
    const int pos0 = tile * 16;
    const int y = tile >> 2, x0 = (tile & 3) * 16;
    const int tid = threadIdx.x;

    {
        const int px = tid & 15, g = tid >> 4;
        const int xp = x0 + px;
        float s = 0.f;
        for (int j = g; j < 49; j += 16) {
            int yy = y + j / 7 - 3, xx = xp + j % 7 - 3;
            if (yy < 0 || yy > 63 || xx < 0 || xx > 63) continue;
            size_t idx = (size_t)(j * BN + b) * HWP + yy * 64 + xx;
            s += part_a[idx] + part_a[idx + 802816] + part_b[idx];
        }
        sattn[px][g] = s;
    }
    __syncthreads();
    if (tid < 16) {
        float t = sa_b[0];
        #pragma unroll
        for (int g = 0; g < 16; g++) t += sattn[tid][g];
        lattn[tid] = 1.f / (1.f + expf(-t));
    }
    __syncthreads();

    const int lane = tid & 63, wv = tid >> 6;
    const int quad = lane >> 4, l16 = lane & 15;

    f32x4 acc[4] = {f32x4{0,0,0,0}, f32x4{0,0,0,0}, f32x4{0,0,0,0}, f32x4{0,0,0,0}};
    const bf16* fb = combined + ((size_t)b * HWP + pos0 + l16) * 384 + quad * 8;
    const bf16* wl0 = wFf + (size_t)wv * 24576 + lane * 8;

    sh8 af[4], afn[4], bf, bfn;
    bf = *(const sh8*)(fb);
    #pragma unroll
    for (int mt = 0; mt < 4; mt++) af[mt] = *(const sh8*)(wl0 + mt * 512);
    for (int kt = 0; kt < 12; kt++) {
        if (kt < 11) {
            bfn = *(const sh8*)(fb + (kt + 1) * 32);
            #pragma unroll
            for (int mt = 0; mt < 4; mt++)
                afn[mt] = *(const sh8*)(wl0 + ((kt + 1) * 4 + mt) * 512);
        }
        #pragma unroll
        for (int mt = 0; mt < 4; mt++)
            acc[mt] = __builtin_amdgcn_mfma_f32_16x16x32_bf16(af[mt], bf, acc[mt], 0, 0, 0);
        bf = bfn;
        #pragma unroll
        for (int mt = 0; mt < 4; mt++) af[mt] = afn[mt];
    }

    float a = lattn[l16];
    float* op = out + (size_t)b * COUT * HWP + pos0 + l16;
    #pragma unroll
    for (int mt = 0; mt < 4; mt++) {
        int co_b = wv * 64 + mt * 16 + quad * 4;
        #pragma unroll
        for (int r = 0; r < 4; r++) {
            int co = co_b + r;
            float o = fmaxf(acc[mt][r] * a * fab[co] + fab[256 + co], 0.f);
            op[(size_t)co * HWP] = o;
        }
    }
}

// ================================================================ launch
extern "C" void kernel_launch(void* const* d_in, const int* in_sizes, int n_in,
                              void* d_out, int out_size, void* d_ws, size_t ws_size,
                              hipStream_t stream)
{
    const float* x      = (const float*)d_in[0];
    const float* oc1_w  = (const float*)d_in[1];
    const float* oc1_b  = (const float*)d_in[2];
    const float* obn_g  = (const float*)d_in[3];
    const float* obn_b  = (const float*)d_in[4];
    const float* obn_m  = (const float*)d_in[5];
    const float* obn_v  = (const float*)d_in[6];
    const float* oc2_w  = (const float*)d_in[7];
    const float* oc2_b  = (const float*)d_in[8];
    const float* mc1_w  = (const float*)d_in[9];
    const float* mc1_b  = (const float*)d_in[10];
    const float* mbn_g  = (const float*)d_in[11];
    const float* mbn_b  = (const float*)d_in[12];
    const float* mbn_m  = (const float*)d_in[13];
    const float* mbn_v  = (const float*)d_in[14];
    const float* mc2_w  = (const float*)d_in[15];
    const float* mc2_b  = (const float*)d_in[16];
    const float* dc_w   = (const float*)d_in[17];
    const float* dc_b   = (const float*)d_in[18];
    const float* cb_dw_w= (const float*)d_in[19];
    const float* cb_dw_b= (const float*)d_in[20];
    const float* cbn_g  = (const float*)d_in[21];
    const float* cbn_b  = (const float*)d_in[22];
    const float* cbn_m  = (const float*)d_in[23];
    const float* cbn_v  = (const float*)d_in[24];
    const float* cb_pw_w= (const float*)d_in[25];
    const float* cb_pw_b= (const float*)d_in[26];
    const float* sa_w   = (const float*)d_in[27];
    const float* sa_b   = (const float*)d_in[28];
    const float* fu_w   = (const float*)d_in[29];
    const float* fu_b   = (const float*)d_in[30];
    const float* fbn_g  = (const float*)d_in[31];
    const float* fbn_b  = (const float*)d_in[32];
    const float* fbn_m  = (const float*)d_in[33];
    const float* fbn_v  = (const float*)d_in[34];

    // workspace layout
    bf16*  ht     = (bf16*)d_ws;                 // 1,048,576 bf16
    bf16*  comb   = ht + 1048576;                // 6,291,456 bf16
    float* part_a = (float*)(comb + 6291456);    // 1,605,632 f32 (2 co-halves)
    float* part_b = part_a + 1605632;            //   802,816 f32
    bf16*  xt     = (bf16*)(part_b + 802816);    // 2,097,152 bf16
    bf16*  wBf2   = xt + 2097152;                //   294,912 bf16
    bf16*  wCf2   = wBf2 + 294912;               //    73,728 bf16
    float* ab     = (float*)(wCf2 + 73728);      //       128 f32
    bf16*  wFf    = (bf16*)(ab + 128);           //    98,304 bf16
    bf16*  wSAf   = wFf + 98304;                 //    24,576 bf16
    float* fab    = (float*)(wSAf + 24576);      //       512 f32
    bf16*  wDf    = (bf16*)(fab + 512);          //    18,432 bf16
    bf16*  wPf    = wDf + 18432;                 //    16,384 bf16
    float* dwab   = (float*)(wPf + 16384);       //       256 f32

    float* out = (float*)d_out;

    // 1. x transpose + all weight preps
    prep_all_kernel<<<256 + 2058, 256, 0, stream>>>(
        x, xt,
        dc_w, oc1_w, oc1_b, obn_g, obn_b, obn_m, obn_v,
        mc1_w, mc1_b, mbn_g, mbn_b, mbn_m, mbn_v,
        fu_w, fu_b, fbn_g, fbn_b, fbn_m, fbn_v, sa_w,
        oc2_w, mc2_w, cb_pw_w, cb_dw_b, cbn_g, cbn_b, cbn_m, cbn_v,
        wBf2, wCf2, ab, wFf, wSAf, fab, wDf, wPf, dwab);
    // 2. oc1 + mc1 fused MFMA conv (32px K-split) -> ht pixel-major
    conv1_mfma_kernel<<<512, 256, 0, stream>>>(xt, wCf2, ab, ht);
    // 3. fused contour dw + pw + SA(contour) -> comb[:,256:384], part_b
    dwpw_kernel<<<1024, 256, 0, stream>>>(xt, cb_dw_w, dwab, wPf, cb_pw_b, wSAf, comb, part_b);
    // 4. fused conv2 + deform + SA(main), co-split -> comb[:,0:256], part_a halves
    deform_kernel<<<1024, 256, 0, stream>>>(xt, ht, wDf, oc2_b, mc2_b, wBf2, dc_b, wSAf, comb, part_a);
    // 5. fusion 1x1 MFMA (+in-block attn from part_a0+part_a1+part_b) -> fp32 out
    fuse_kernel<<<1024, 256, 0, stream>>>(comb, part_a, part_b, sa_b, wFf, fab, out);
}

// Round 14
// 200.531 us; speedup vs baseline: 1.0328x; 1.0328x over previous
//
#include <hip/hip_runtime.h>
#include <hip/hip_bf16.h>
#include <math.h>

// Problem constants
#define BN   4
#define CIN  128
#define COUT 256
#define HWP  4096      // 64*64

typedef __hip_bfloat16 bf16;
typedef __attribute__((ext_vector_type(8))) short sh8;    // 8 bf16 = 4 VGPR
typedef __attribute__((ext_vector_type(4))) float f32x4;  // MFMA accumulator

__device__ __forceinline__ float b2f(bf16 v) { return __bfloat162float(v); }
__device__ __forceinline__ float bflo(unsigned u) { return __uint_as_float(u << 16); }
__device__ __forceinline__ float bfhi(unsigned u) { return __uint_as_float(u & 0xffff0000u); }
__device__ __forceinline__ unsigned short f2bfbits(float f) {
    union { bf16 h; unsigned short u; } cv; cv.h = __float2bfloat16(f); return cv.u;
}
__device__ __forceinline__ float bfj(const uint4& c, int j) {
    unsigned u = (&c.x)[j >> 1];
    return (j & 1) ? bfhi(u) : bflo(u);
}

// ---------------------------------------------------------------- prep_all (+x transpose in blocks [0,256))
__global__ __launch_bounds__(256) void prep_all_kernel(
    const float* __restrict__ x, bf16* __restrict__ xt,
    const float* __restrict__ dc_w,
    const float* __restrict__ oc1_w, const float* __restrict__ oc1_b,
    const float* __restrict__ obn_g, const float* __restrict__ obn_b,
    const float* __restrict__ obn_m, const float* __restrict__ obn_v,
    const float* __restrict__ mc1_w, const float* __restrict__ mc1_b,
    const float* __restrict__ mbn_g, const float* __restrict__ mbn_b,
    const float* __restrict__ mbn_m, const float* __restrict__ mbn_v,
    const float* __restrict__ fu_w, const float* __restrict__ fu_b,
    const float* __restrict__ fbn_g, const float* __restrict__ fbn_b,
    const float* __restrict__ fbn_m, const float* __restrict__ fbn_v,
    const float* __restrict__ sa_w,
    const float* __restrict__ oc2_w, const float* __restrict__ mc2_w,
    const float* __restrict__ cb_pw_w,
    const float* __restrict__ cb_dw_b, const float* __restrict__ cbn_g,
    const float* __restrict__ cbn_b, const float* __restrict__ cbn_m,
    const float* __restrict__ cbn_v,
    bf16* __restrict__ wBf2, bf16* __restrict__ wCf2, float* __restrict__ ab,
    bf16* __restrict__ wFf, bf16* __restrict__ wSAf, float* __restrict__ fab,
    bf16* __restrict__ wDf, bf16* __restrict__ wPf, float* __restrict__ dwab)
{
    __shared__ bf16 t[64][136];
    if (blockIdx.x < 256) {
        const int b = blockIdx.x >> 6, chunk = blockIdx.x & 63;
        const int pos0 = chunk * 64;
        const int tid = threadIdx.x;
        const int lane = tid & 63, wv = tid >> 6;
        const float* xb = x + (size_t)b * CIN * HWP + pos0 + lane;
        #pragma unroll 4
        for (int j = 0; j < 32; j++) {
            int ci = wv * 32 + j;
            t[lane][ci] = __float2bfloat16(xb[(size_t)ci * HWP]);
        }
        __syncthreads();
        const int p = tid >> 2, cig = tid & 3;
        uint4* dst = (uint4*)(xt + ((size_t)b * HWP + pos0 + p) * 128 + cig * 32);
        const uint4* src = (const uint4*)&t[p][cig * 32];
        #pragma unroll
        for (int q = 0; q < 4; q++) dst[q] = src[q];
        return;
    }

    int o = (blockIdx.x - 256) * 256 + threadIdx.x;
    if (o < 294912) {
        int j = o & 7, o2 = o >> 3;
        int lane = o2 & 63, t_ = o2 >> 6;
        int l16 = lane & 15, quad = lane >> 4;
        int mt = t_ & 3, t2 = t_ >> 2;
        int kt = t2 % 18, t3 = t2 / 18;
        int h = t3 & 1, wv = t3 >> 1;
        int co = wv * 64 + mt * 16 + l16;
        int kkh = kt * 32 + quad * 8 + j;
        int k = kkh >> 6, ci = h * 64 + (kkh & 63);
        wBf2[o] = __float2bfloat16(dc_w[co * 1152 + ci * 9 + k]);
    } else if (o < 368640) {
        int idx = o - 294912;
        int j = idx & 7, o2 = idx >> 3;
        int lane = o2 & 63, t_ = o2 >> 6;
        int l16 = lane & 15, quad = lane >> 4;
        int kt = t_ % 18, t2 = t_ / 18;
        int h = t2 & 1, wv = t2 >> 1;
        int co = wv * 16 + l16;
        int kkh = kt * 32 + quad * 8 + j;
        int k = kkh >> 6, ci = h * 64 + (kkh & 63);
        float v = (co < 32) ? oc1_w[co * 1152 + ci * 9 + k]
                            : mc1_w[(co - 32) * 1152 + ci * 9 + k];
        wCf2[idx] = __float2bfloat16(v);
    } else if (o < 368704) {
        int c = o - 368640;
        float g, bb, m, vv, bias;
        if (c < 32) { g = obn_g[c]; bb = obn_b[c]; m = obn_m[c]; vv = obn_v[c]; bias = oc1_b[c]; }
        else { int c2 = c - 32; g = mbn_g[c2]; bb = mbn_b[c2]; m = mbn_m[c2]; vv = mbn_v[c2]; bias = mc1_b[c2]; }
        float alpha = g / sqrtf(vv + 1e-5f);
        ab[c] = alpha;
        ab[64 + c] = (bias - m) * alpha + bb;
    } else if (o < 467008) {
        int idx = o - 368704;
        int j = idx & 7, o2 = idx >> 3;
        int lane = o2 & 63, t_ = o2 >> 6;
        int l16 = lane & 15, quad = lane >> 4;
        int mt = t_ & 3, t2 = t_ >> 2;
        int kt = t2 % 12, wv = t2 / 12;
        int co = wv * 64 + mt * 16 + l16;
        int kk = kt * 32 + quad * 8 + j;
        wFf[idx] = __float2bfloat16(fu_w[co * 384 + kk]);
    } else if (o < 491584) {
        int idx = o - 467008;
        int j = idx & 7, o2 = idx >> 3;
        int lane = o2 & 63, t_ = o2 >> 6;
        int l16 = lane & 15, quad = lane >> 4;
        int kt = t_ % 12, wv = t_ / 12;
        int jr = wv * 16 + l16;
        int kk = kt * 32 + quad * 8 + j;
        wSAf[idx] = (jr < 49) ? __float2bfloat16(sa_w[kk * 49 + jr]) : __float2bfloat16(0.f);
    } else if (o < 491840) {
        int co = o - 491584;
        float alpha = fbn_g[co] / sqrtf(fbn_v[co] + 1e-5f);
        fab[co] = alpha;
        fab[256 + co] = (fu_b[co] - fbn_m[co]) * alpha + fbn_b[co];
    } else if (o < 510272) {
        int idx = o - 491840;
        int j = idx & 7, o2 = idx >> 3;
        int lane = o2 & 63, t_ = o2 >> 6;
        int l16 = lane & 15, quad = lane >> 4;
        int mt = t_ & 1, kt = t_ >> 1;
        int co = mt * 16 + l16;
        int kk = kt * 32 + quad * 8 + j;
        int k = kk >> 6, c = kk & 63;
        float v = 0.f;
        if (co < 18 && c < 32) v = oc2_w[co * 288 + c * 9 + k];
        else if (co >= 18 && co < 27 && c >= 32) v = mc2_w[(co - 18) * 288 + (c - 32) * 9 + k];
        wDf[idx] = __float2bfloat16(v);
    } else if (o < 526656) {
        int idx = o - 510272;
        int j = idx & 7, o2 = idx >> 3;
        int lane = o2 & 63, t_ = o2 >> 6;
        int l16 = lane & 15, quad = lane >> 4;
        int wv = t_ >> 3, kt = (t_ >> 1) & 3, mt = t_ & 1;
        int co = wv * 32 + mt * 16 + l16;
        int kk = kt * 32 + quad * 8 + j;
        wPf[idx] = __float2bfloat16(cb_pw_w[co * 128 + kk]);
    } else if (o < 526784) {
        int c = o - 526656;
        float alpha = cbn_g[c] / sqrtf(cbn_v[c] + 1e-5f);
        dwab[c] = alpha;
        dwab[128 + c] = (cb_dw_b[c] - cbn_m[c]) * alpha + cbn_b[c];
    }
}

// ---------------------------------------------------------------- conv1 (oc1+mc1) MFMA, 32px K-split -> ht
__global__ __launch_bounds__(256) void conv1_mfma_kernel(
    const bf16* __restrict__ xt, const bf16* __restrict__ wCf2, const float* __restrict__ ab,
    bf16* __restrict__ ht)
{
    __shared__ __align__(16) bf16 val[32][584];

    const int bid = blockIdx.x;
    const int b = (bid & 7) >> 1;
    const int tile = ((bid >> 3) << 1) | (bid & 1);
    const int pos0 = tile * 32;
    const int y = tile >> 1, x0 = (tile & 1) * 32;
    const int tid = threadIdx.x;
    const int lane = tid & 63, wv = tid >> 6;
    const int quad = lane >> 4, l16 = lane & 15;

    f32x4 acc[2] = {f32x4{0,0,0,0}, f32x4{0,0,0,0}};
    const bf16* xtb = xt + (size_t)b * HWP * 128;

    #pragma unroll
    for (int h = 0; h < 2; h++) {
        if (h) __syncthreads();
        {
            const int cig = tid & 7, pix = tid >> 3;
            const int ci0 = h * 64 + cig * 8;
            const int xxp = x0 + pix;
            #pragma unroll
            for (int k = 0; k < 9; k++) {
                int yy = y + k / 3 - 1, xx = xxp + k % 3 - 1;
                bool valid = (yy >= 0 && yy <= 63 && xx >= 0 && xx <= 63);
                uint4 c = {0, 0, 0, 0};
                if (valid) c = *(const uint4*)(xtb + (size_t)(yy * 64 + xx) * 128 + ci0);
                *(uint4*)&val[pix][k * 64 + cig * 8] = c;
            }
        }
        __syncthreads();

        const bf16* wl0 = wCf2 + ((size_t)(wv * 2 + h) * 18) * 512 + lane * 8;
        const bf16* vb0 = &val[l16][quad * 8];
        const bf16* vb1 = &val[16 + l16][quad * 8];
        for (int kt = 0; kt < 18; kt++) {
            sh8 af = *(const sh8*)(wl0 + kt * 512);
            sh8 b0 = *(const sh8*)(vb0 + kt * 32);
            sh8 b1 = *(const sh8*)(vb1 + kt * 32);
            acc[0] = __builtin_amdgcn_mfma_f32_16x16x32_bf16(af, b0, acc[0], 0, 0, 0);
            acc[1] = __builtin_amdgcn_mfma_f32_16x16x32_bf16(af, b1, acc[1], 0, 0, 0);
        }
    }

    const int co0 = wv * 16 + quad * 4;
    #pragma unroll
    for (int ph = 0; ph < 2; ph++) {
        float o0 = fmaxf(acc[ph][0] * ab[co0 + 0] + ab[64 + co0 + 0], 0.f);
        float o1 = fmaxf(acc[ph][1] * ab[co0 + 1] + ab[64 + co0 + 1], 0.f);
        float o2 = fmaxf(acc[ph][2] * ab[co0 + 2] + ab[64 + co0 + 2], 0.f);
        float o3 = fmaxf(acc[ph][3] * ab[co0 + 3] + ab[64 + co0 + 3], 0.f);
        uint2 pk;
        pk.x = (unsigned)f2bfbits(o0) | ((unsigned)f2bfbits(o1) << 16);
        pk.y = (unsigned)f2bfbits(o2) | ((unsigned)f2bfbits(o3) << 16);
        *(uint2*)(ht + ((size_t)b * HWP + pos0 + ph * 16 + l16) * 64 + co0) = pk;
    }
}

// ---------------------------------------------------------------- fused depthwise + pointwise + SA(contour)
__global__ __launch_bounds__(256) void dwpw_kernel(
    const bf16* __restrict__ xt, const float* __restrict__ dw_w, const float* __restrict__ dwab,
    const bf16* __restrict__ wPf, const float* __restrict__ pw_b,
    const bf16* __restrict__ wSAf, bf16* __restrict__ combined, float* __restrict__ part_b)
{
    __shared__ float wl[1152];
    __shared__ float abl[256];
    __shared__ __align__(16) bf16 vdw[16][136];
    const int bid = blockIdx.x;
    const int b = bid >> 8, tile = bid & 255;
    const int pos0 = tile * 16;
    const int y = tile >> 2, x0 = (tile & 3) * 16;
    const int tid = threadIdx.x;
    for (int i = tid; i < 1152; i += 256) wl[i] = dw_w[i];
    abl[tid] = dwab[tid];
    __syncthreads();

    {
        const int cig = tid & 15, pix = tid >> 4;
        const int ci0 = cig * 8;
        const int xxp = x0 + pix;
        const bf16* xtb = xt + (size_t)b * HWP * 128;
        float g[8] = {0, 0, 0, 0, 0, 0, 0, 0};
        #pragma unroll
        for (int k = 0; k < 9; k++) {
            int yy = y + k / 3 - 1, xx = xxp + k % 3 - 1;
            if (yy < 0 || yy > 63 || xx < 0 || xx > 63) continue;
            uint4 c = *(const uint4*)(xtb + (size_t)(yy * 64 + xx) * 128 + ci0);
            #pragma unroll
            for (int j = 0; j < 8; j++)
                g[j] += wl[(ci0 + j) * 9 + k] * bfj(c, j);
        }
        uint4 pk;
        float o[8];
        #pragma unroll
        for (int j = 0; j < 8; j++)
            o[j] = fmaxf(g[j] * abl[ci0 + j] + abl[128 + ci0 + j], 0.f);
        pk.x = (unsigned)f2bfbits(o[0]) | ((unsigned)f2bfbits(o[1]) << 16);
        pk.y = (unsigned)f2bfbits(o[2]) | ((unsigned)f2bfbits(o[3]) << 16);
        pk.z = (unsigned)f2bfbits(o[4]) | ((unsigned)f2bfbits(o[5]) << 16);
        pk.w = (unsigned)f2bfbits(o[6]) | ((unsigned)f2bfbits(o[7]) << 16);
        *(uint4*)&vdw[pix][ci0] = pk;
    }
    __syncthreads();

    const int lane = tid & 63, wv = tid >> 6;
    const int quad = lane >> 4, l16 = lane & 15;
    f32x4 acc[2] = {f32x4{0,0,0,0}, f32x4{0,0,0,0}};
    const bf16* fb = &vdw[l16][quad * 8];
    const bf16* wl0 = wPf + (size_t)wv * 4096 + lane * 8;
    #pragma unroll
    for (int kt = 0; kt < 4; kt++) {
        sh8 bf = *(const sh8*)(fb + kt * 32);
        #pragma unroll
        for (int mt = 0; mt < 2; mt++) {
            sh8 af = *(const sh8*)(wl0 + (kt * 2 + mt) * 512);
            acc[mt] = __builtin_amdgcn_mfma_f32_16x16x32_bf16(af, bf, acc[mt], 0, 0, 0);
        }
    }

    bf16* ct = combined + ((size_t)b * HWP + pos0 + l16) * 384 + 256;
    uint2 pko[2];
    #pragma unroll
    for (int mt = 0; mt < 2; mt++) {
        int co_b = wv * 32 + mt * 16 + quad * 4;
        uint2 pk;
        pk.x = (unsigned)f2bfbits(acc[mt][0] + pw_b[co_b])     | ((unsigned)f2bfbits(acc[mt][1] + pw_b[co_b + 1]) << 16);
        pk.y = (unsigned)f2bfbits(acc[mt][2] + pw_b[co_b + 2]) | ((unsigned)f2bfbits(acc[mt][3] + pw_b[co_b + 3]) << 16);
        *(uint2*)(ct + co_b) = pk;
        pko[mt] = pk;
    }

    // ---- Phase3: SA contribution for contour channels (global kt 8..11)
    __syncthreads();
    bf16* ct2 = &vdw[0][0];
    #pragma unroll
    for (int mt = 0; mt < 2; mt++) {
        int co_b = wv * 32 + mt * 16 + quad * 4;
        *(uint2*)(ct2 + l16 * 136 + co_b) = pko[mt];
    }
    __syncthreads();

    f32x4 sacc = {0, 0, 0, 0};
    const bf16* awl = wSAf + (size_t)wv * 6144 + lane * 8;
    #pragma unroll
    for (int kt2 = 0; kt2 < 4; kt2++) {
        sh8 af = *(const sh8*)(awl + (8 + kt2) * 512);
        sh8 bf2 = *(const sh8*)(ct2 + l16 * 136 + kt2 * 32 + quad * 8);
        sacc = __builtin_amdgcn_mfma_f32_16x16x32_bf16(af, bf2, sacc, 0, 0, 0);
    }
    #pragma unroll
    for (int r = 0; r < 4; r++) {
        int j = wv * 16 + quad * 4 + r;
        if (j < 49) part_b[(size_t)(j * BN + b) * HWP + pos0 + l16] = sacc[r];
    }
}

// ---------------------------------------------------------------- fused conv2 + deform + SA(main)
// grid 512, block 256 = 4 waves. LDS ~49 KB.
__global__ __launch_bounds__(256) void deform_kernel(
    const bf16* __restrict__ xt, const bf16* __restrict__ ht, const bf16* __restrict__ wDf,
    const float* __restrict__ oc2_b, const float* __restrict__ mc2_b,
    const bf16* __restrict__ wBf2, const float* __restrict__ bias,
    const bf16* __restrict__ wSAf, bf16* __restrict__ combined, float* __restrict__ part_a)
{
    __shared__ __align__(16) bf16 val[32][584];
    __shared__ int   ti[288][4];
    __shared__ float tw[288][4];
    __shared__ float loff[18][32];
    __shared__ float lmsk[9][32];

    const int bid = blockIdx.x;
    const int b = (bid & 7) >> 1;                    // XCD-affinity
    const int tile = ((bid >> 3) << 1) | (bid & 1);  // [0,128)
    const int pos0 = tile * 32;
    const int y = tile >> 1, x0 = (tile & 1) * 32;
    const int tid = threadIdx.x;
    const int lane = tid & 63, wv = tid >> 6;
    const int quad = lane >> 4, l16 = lane & 15;

    // ---- Phase A: conv2 (oc2+mc2) for this tile's 32 pixels
    {
        const int cig = tid & 7, pix = tid >> 3;
        const int xxp = x0 + pix;
        const bf16* hb = ht + (size_t)b * HWP * 64;
        #pragma unroll
        for (int k = 0; k < 9; k++) {
            int yy = y + k / 3 - 1, xx = xxp + k % 3 - 1;
            bool valid = (yy >= 0 && yy <= 63 && xx >= 0 && xx <= 63);
            uint4 c = {0, 0, 0, 0};
            if (valid) c = *(const uint4*)(hb + (size_t)(yy * 64 + xx) * 64 + cig * 8);
            *(uint4*)&val[pix][k * 64 + cig * 8] = c;
        }
    }
    __syncthreads();
    {
        const int ph = wv >> 1, mt = wv & 1;
        f32x4 acc2 = {0, 0, 0, 0};
        const bf16* wl0 = wDf + ((size_t)mt * 64 + lane) * 8;
        const bf16* vbase = &val[ph * 16 + l16][quad * 8];
        for (int kt = 0; kt < 18; kt++) {
            sh8 af = *(const sh8*)(wl0 + kt * 1024);
            sh8 bf = *(const sh8*)(vbase + kt * 32);
            acc2 = __builtin_amdgcn_mfma_f32_16x16x32_bf16(af, bf, acc2, 0, 0, 0);
        }
        const int pix2 = ph * 16 + l16;
        #pragma unroll
        for (int r = 0; r < 4; r++) {
            int co = mt * 16 + quad * 4 + r;
            if (co < 18) {
                loff[co][pix2] = acc2[r] + oc2_b[co];
            } else if (co < 27) {
                float s = acc2[r] + mc2_b[co - 18];
                lmsk[co - 18][pix2] = 1.f / (1.f + expf(-s));
            }
        }
    }
    __syncthreads();

    // ---- Phase B: bilinear corner tables
    for (int e = tid; e < 288; e += 256) {
        int k = e >> 5, pix = e & 31;
        int pos = pos0 + pix;
        int yp = pos >> 6, xc = pos & 63;
        float offy = loff[2 * k][pix];
        float offx = loff[2 * k + 1][pix];
        float m = lmsk[k][pix];
        float py = (float)(yp - 1 + k / 3) + offy;
        float px = (float)(xc - 1 + k % 3) + offx;
        float fy = floorf(py), fx = floorf(px);
        float wy1 = py - fy, wx1 = px - fx;
        int y0 = (int)fy, x0c = (int)fx;
        int y1 = y0 + 1, x1 = x0c + 1;
        bool vy0 = (y0 >= 0 && y0 <= 63), vy1 = (y1 >= 0 && y1 <= 63);
        bool vx0 = (x0c >= 0 && x0c <= 63), vx1 = (x1 >= 0 && x1 <= 63);
        int cy0 = min(max(y0, 0), 63), cy1 = min(max(y1, 0), 63);
        int cx0 = min(max(x0c, 0), 63), cx1 = min(max(x1, 0), 63);
        ti[e][0] = cy0 * 64 + cx0;  tw[e][0] = (vy0 && vx0) ? (1.f - wy1) * (1.f - wx1) * m : 0.f;
        ti[e][1] = cy0 * 64 + cx1;  tw[e][1] = (vy0 && vx1) ? (1.f - wy1) * wx1 * m : 0.f;
        ti[e][2] = cy1 * 64 + cx0;  tw[e][2] = (vy1 && vx0) ? wy1 * (1.f - wx1) * m : 0.f;
        ti[e][3] = cy1 * 64 + cx1;  tw[e][3] = (vy1 && vx1) ? wy1 * wx1 * m : 0.f;
    }
    __syncthreads();

    // ---- Phase C/D: K-split gather + MFMA
    f32x4 acc[4][2] = {{f32x4{0,0,0,0}, f32x4{0,0,0,0}}, {f32x4{0,0,0,0}, f32x4{0,0,0,0}},
                       {f32x4{0,0,0,0}, f32x4{0,0,0,0}}, {f32x4{0,0,0,0}, f32x4{0,0,0,0}}};
    const bf16* xtb = xt + (size_t)b * HWP * 128;

    #pragma unroll
    for (int h = 0; h < 2; h++) {
        if (h) __syncthreads();
        {
            const int cig = tid & 7, pix = tid >> 3;
            const int ci0 = h * 64 + cig * 8;
            for (int k = 0; k < 9; k++) {
                const int e = k * 32 + pix;
                const int i0 = ti[e][0], i1 = ti[e][1], i2 = ti[e][2], i3 = ti[e][3];
                const float w0 = tw[e][0], w1 = tw[e][1], w2 = tw[e][2], w3 = tw[e][3];
                uint4 c0 = *(const uint4*)(xtb + (size_t)i0 * 128 + ci0);
                uint4 c1 = *(const uint4*)(xtb + (size_t)i1 * 128 + ci0);
                uint4 c2 = *(const uint4*)(xtb + (size_t)i2 * 128 + ci0);
                uint4 c3 = *(const uint4*)(xtb + (size_t)i3 * 128 + ci0);
                float g[8];
                #pragma unroll
                for (int j = 0; j < 8; j++)
                    g[j] = w0 * bfj(c0, j) + w1 * bfj(c1, j) + w2 * bfj(c2, j) + w3 * bfj(c3, j);
                uint4 pk;
                pk.x = (unsigned)f2bfbits(g[0]) | ((unsigned)f2bfbits(g[1]) << 16);
                pk.y = (unsigned)f2bfbits(g[2]) | ((unsigned)f2bfbits(g[3]) << 16);
                pk.z = (unsigned)f2bfbits(g[4]) | ((unsigned)f2bfbits(g[5]) << 16);
                pk.w = (unsigned)f2bfbits(g[6]) | ((unsigned)f2bfbits(g[7]) << 16);
                *(uint4*)&val[pix][k * 64 + cig * 8] = pk;
            }
        }
        __syncthreads();

        const bf16* wl0 = wBf2 + ((size_t)(wv * 2 + h) * 72) * 512 + lane * 8;
        const bf16* vb0 = &val[l16][quad * 8];
        const bf16* vb1 = &val[16 + l16][quad * 8];
        sh8 af[4], afn[4];
        #pragma unroll
        for (int mt = 0; mt < 4; mt++) af[mt] = *(const sh8*)(wl0 + mt * 512);
        for (int kt = 0; kt < 18; kt++) {
            sh8 b0 = *(const sh8*)(vb0 + kt * 32);
            sh8 b1 = *(const sh8*)(vb1 + kt * 32);
            if (kt < 17) {
                #pragma unroll
                for (int mt = 0; mt < 4; mt++)
                    afn[mt] = *(const sh8*)(wl0 + ((kt + 1) * 4 + mt) * 512);
            }
            #pragma unroll
            for (int mt = 0; mt < 4; mt++) {
                acc[mt][0] = __builtin_amdgcn_mfma_f32_16x16x32_bf16(af[mt], b0, acc[mt][0], 0, 0, 0);
                acc[mt][1] = __builtin_amdgcn_mfma_f32_16x16x32_bf16(af[mt], b1, acc[mt][1], 0, 0, 0);
            }
            #pragma unroll
            for (int mt = 0; mt < 4; mt++) af[mt] = afn[mt];
        }
    }

    // ---- epilogue: global comb write + LDS transpose for SA
    uint2 pko[4][2];
    #pragma unroll
    for (int ph = 0; ph < 2; ph++) {
        bf16* ct = combined + ((size_t)b * HWP + pos0 + ph * 16 + l16) * 384;
        #pragma unroll
        for (int mt = 0; mt < 4; mt++) {
            int co_b = wv * 64 + mt * 16 + quad * 4;
            uint2 pk;
            pk.x = (unsigned)f2bfbits(acc[mt][ph][0] + bias[co_b])     | ((unsigned)f2bfbits(acc[mt][ph][1] + bias[co_b + 1]) << 16);
            pk.y = (unsigned)f2bfbits(acc[mt][ph][2] + bias[co_b + 2]) | ((unsigned)f2bfbits(acc[mt][ph][3] + bias[co_b + 3]) << 16);
            *(uint2*)(ct + co_b) = pk;
            pko[mt][ph] = pk;
        }
    }

    // ---- Phase E: SA for main channels (global kt 0..7); reuse val as ctile[pix][co] stride 264
    __syncthreads();                          // all MFMA B-reads of val done
    bf16* ctile = &val[0][0];
    #pragma unroll
    for (int ph = 0; ph < 2; ph++) {
        int pix = ph * 16 + l16;
        #pragma unroll
        for (int mt = 0; mt < 4; mt++) {
            int co_b = wv * 64 + mt * 16 + quad * 4;
            *(uint2*)(ctile + pix * 264 + co_b) = pko[mt][ph];
        }
    }
    __syncthreads();

    f32x4 sacc[2] = {f32x4{0,0,0,0}, f32x4{0,0,0,0}};
    const bf16* awl = wSAf + (size_t)wv * 6144 + lane * 8;
    for (int kt = 0; kt < 8; kt++) {
        sh8 af = *(const sh8*)(awl + kt * 512);
        sh8 b0 = *(const sh8*)(ctile + l16 * 264 + kt * 32 + quad * 8);
        sh8 b1 = *(const sh8*)(ctile + (16 + l16) * 264 + kt * 32 + quad * 8);
        sacc[0] = __builtin_amdgcn_mfma_f32_16x16x32_bf16(af, b0, sacc[0], 0, 0, 0);
        sacc[1] = __builtin_amdgcn_mfma_f32_16x16x32_bf16(af, b1, sacc[1], 0, 0, 0);
    }
    #pragma unroll
    for (int ph = 0; ph < 2; ph++) {
        #pragma unroll
        for (int r = 0; r < 4; r++) {
            int j = wv * 16 + quad * 4 + r;
            if (j < 49) part_a[(size_t)(j * BN + b) * HWP + pos0 + ph * 16 + l16] = sacc[ph][r];
        }
    }
}

// ---------------------------------------------------------------- fusion 1x1 MFMA + in-block attn finalize
__global__ __launch_bounds__(256) void fuse_kernel(
    const bf16* __restrict__ combined, const float* __restrict__ part_a, const float* __restrict__ part_b,
    const float* __restrict__ sa_b,
    const bf16* __restrict__ wFf, const float* __restrict__ fab, float* __restrict__ out)
{
    __shared__ float sattn[16][17];
    __shared__ float lattn[16];

    const int bid = blockIdx.x;
    const int b = bid >> 8, tile = bid & 255;
    const int pos0 = tile * 16;
    const int y = tile >> 2, x0 = (tile & 3) * 16;
    const int tid = threadIdx.x;

    {
        const int px = tid & 15, g = tid >> 4;
        const int xp = x0 + px;
        float s = 0.f;
        for (int j = g; j < 49; j += 16) {
            int yy = y + j / 7 - 3, xx = xp + j % 7 - 3;
            if (yy < 0 || yy > 63 || xx < 0 || xx > 63) continue;
            size_t idx = (size_t)(j * BN + b) * HWP + yy * 64 + xx;
            s += part_a[idx] + part_b[idx];
        }
        sattn[px][g] = s;
    }
    __syncthreads();
    if (tid < 16) {
        float t = sa_b[0];
        #pragma unroll
        for (int g = 0; g < 16; g++) t += sattn[tid][g];
        lattn[tid] = 1.f / (1.f + expf(-t));
    }
    __syncthreads();

    const int lane = tid & 63, wv = tid >> 6;
    const int quad = lane >> 4, l16 = lane & 15;

    f32x4 acc[4] = {f32x4{0,0,0,0}, f32x4{0,0,0,0}, f32x4{0,0,0,0}, f32x4{0,0,0,0}};
    const bf16* fb = combined + ((size_t)b * HWP + pos0 + l16) * 384 + quad * 8;
    const bf16* wl0 = wFf + (size_t)wv * 24576 + lane * 8;

    sh8 af[4], afn[4], bf, bfn;
    bf = *(const sh8*)(fb);
    #pragma unroll
    for (int mt = 0; mt < 4; mt++) af[mt] = *(const sh8*)(wl0 + mt * 512);
    for (int kt = 0; kt < 12; kt++) {
        if (kt < 11) {
            bfn = *(const sh8*)(fb + (kt + 1) * 32);
            #pragma unroll
            for (int mt = 0; mt < 4; mt++)
                afn[mt] = *(const sh8*)(wl0 + ((kt + 1) * 4 + mt) * 512);
        }
        #pragma unroll
        for (int mt = 0; mt < 4; mt++)
            acc[mt] = __builtin_amdgcn_mfma_f32_16x16x32_bf16(af[mt], bf, acc[mt], 0, 0, 0);
        bf = bfn;
        #pragma unroll
        for (int mt = 0; mt < 4; mt++) af[mt] = afn[mt];
    }

    float a = lattn[l16];
    float* op = out + (size_t)b * COUT * HWP + pos0 + l16;
    #pragma unroll
    for (int mt = 0; mt < 4; mt++) {
        int co_b = wv * 64 + mt * 16 + quad * 4;
        #pragma unroll
        for (int r = 0; r < 4; r++) {
            int co = co_b + r;
            float o = fmaxf(acc[mt][r] * a * fab[co] + fab[256 + co], 0.f);
            op[(size_t)co * HWP] = o;
        }
    }
}

// ================================================================ launch
extern "C" void kernel_launch(void* const* d_in, const int* in_sizes, int n_in,
                              void* d_out, int out_size, void* d_ws, size_t ws_size,
                              hipStream_t stream)
{
    const float* x      = (const float*)d_in[0];
    const float* oc1_w  = (const float*)d_in[1];
    const float* oc1_b  = (const float*)d_in[2];
    const float* obn_g  = (const float*)d_in[3];
    const float* obn_b  = (const float*)d_in[4];
    const float* obn_m  = (const float*)d_in[5];
    const float* obn_v  = (const float*)d_in[6];
    const float* oc2_w  = (const float*)d_in[7];
    const float* oc2_b  = (const float*)d_in[8];
    const float* mc1_w  = (const float*)d_in[9];
    const float* mc1_b  = (const float*)d_in[10];
    const float* mbn_g  = (const float*)d_in[11];
    const float* mbn_b  = (const float*)d_in[12];
    const float* mbn_m  = (const float*)d_in[13];
    const float* mbn_v  = (const float*)d_in[14];
    const float* mc2_w  = (const float*)d_in[15];
    const float* mc2_b  = (const float*)d_in[16];
    const float* dc_w   = (const float*)d_in[17];
    const float* dc_b   = (const float*)d_in[18];
    const float* cb_dw_w= (const float*)d_in[19];
    const float* cb_dw_b= (const float*)d_in[20];
    const float* cbn_g  = (const float*)d_in[21];
    const float* cbn_b  = (const float*)d_in[22];
    const float* cbn_m  = (const float*)d_in[23];
    const float* cbn_v  = (const float*)d_in[24];
    const float* cb_pw_w= (const float*)d_in[25];
    const float* cb_pw_b= (const float*)d_in[26];
    const float* sa_w   = (const float*)d_in[27];
    const float* sa_b   = (const float*)d_in[28];
    const float* fu_w   = (const float*)d_in[29];
    const float* fu_b   = (const float*)d_in[30];
    const float* fbn_g  = (const float*)d_in[31];
    const float* fbn_b  = (const float*)d_in[32];
    const float* fbn_m  = (const float*)d_in[33];
    const float* fbn_v  = (const float*)d_in[34];

    // workspace layout
    bf16*  ht     = (bf16*)d_ws;                 // 1,048,576 bf16
    bf16*  comb   = ht + 1048576;                // 6,291,456 bf16
    float* part_a = (float*)(comb + 6291456);    //   802,816 f32
    float* part_b = part_a + 802816;             //   802,816 f32
    bf16*  xt     = (bf16*)(part_b + 802816);    // 2,097,152 bf16
    bf16*  wBf2   = xt + 2097152;                //   294,912 bf16
    bf16*  wCf2   = wBf2 + 294912;               //    73,728 bf16
    float* ab     = (float*)(wCf2 + 73728);      //       128 f32
    bf16*  wFf    = (bf16*)(ab + 128);           //    98,304 bf16
    bf16*  wSAf   = wFf + 98304;                 //    24,576 bf16
    float* fab    = (float*)(wSAf + 24576);      //       512 f32
    bf16*  wDf    = (bf16*)(fab + 512);          //    18,432 bf16
    bf16*  wPf    = wDf + 18432;                 //    16,384 bf16
    float* dwab   = (float*)(wPf + 16384);       //       256 f32

    float* out = (float*)d_out;

    // 1. x transpose + all weight preps
    prep_all_kernel<<<256 + 2058, 256, 0, stream>>>(
        x, xt,
        dc_w, oc1_w, oc1_b, obn_g, obn_b, obn_m, obn_v,
        mc1_w, mc1_b, mbn_g, mbn_b, mbn_m, mbn_v,
        fu_w, fu_b, fbn_g, fbn_b, fbn_m, fbn_v, sa_w,
        oc2_w, mc2_w, cb_pw_w, cb_dw_b, cbn_g, cbn_b, cbn_m, cbn_v,
        wBf2, wCf2, ab, wFf, wSAf, fab, wDf, wPf, dwab);
    // 2. oc1 + mc1 fused MFMA conv (32px K-split) -> ht pixel-major
    conv1_mfma_kernel<<<512, 256, 0, stream>>>(xt, wCf2, ab, ht);
    // 3. fused contour dw + pw + SA(contour) -> comb[:,256:384], part_b
    dwpw_kernel<<<1024, 256, 0, stream>>>(xt, cb_dw_w, dwab, wPf, cb_pw_b, wSAf, comb, part_b);
    // 4. fused conv2 + deform + SA(main) -> comb[:,0:256], part_a
    deform_kernel<<<512, 256, 0, stream>>>(xt, ht, wDf, oc2_b, mc2_b, wBf2, dc_b, wSAf, comb, part_a);
    // 5. fusion 1x1 MFMA (+in-block attn from part_a+part_b, folded BN, ReLU) -> fp32 out
    fuse_kernel<<<1024, 256, 0, stream>>>(comb, part_a, part_b, sa_b, wFf, fab, out);
}